// Round 1
// baseline (657.470 us; speedup 1.0000x reference)
//
#include <hip/hip_runtime.h>
#include <hip/hip_bf16.h>

#define N 8192
#define D_IN 256
#define HID 512
#define Z 128
#define NCAT 16
#define EPS_F 1e-16f

__device__ __forceinline__ float softplus_f(float x) {
    return fmaxf(x, 0.f) + log1pf(expf(-fabsf(x)));
}

// ---------------- init counters ----------------
__global__ void k_init(float* negsum, int* cnt, int* fill) {
    int n = blockIdx.x * blockDim.x + threadIdx.x;
    if (n < N) negsum[n] = 0.f;
    if (n < NCAT) { cnt[n] = 0; fill[n] = 0; }
}

__global__ void k_count(const int* __restrict__ c, int* cnt) {
    int n = blockIdx.x * blockDim.x + threadIdx.x;
    if (n < N) atomicAdd(&cnt[c[n]], 1);
}

__global__ void k_scan(const int* __restrict__ cnt, int* offs) {
    if (threadIdx.x == 0) {
        int s = 0;
        for (int k = 0; k < NCAT; k++) { offs[k] = s; s += cnt[k]; }
        offs[NCAT] = s;
    }
}

__global__ void k_fill(const int* __restrict__ c, int* fill, const int* __restrict__ offs,
                       int* perm, int* cperm) {
    int n = blockIdx.x * blockDim.x + threadIdx.x;
    if (n < N) {
        int cat = c[n];
        int pos = atomicAdd(&fill[cat], 1);
        int s = offs[cat] + pos;
        perm[s] = n;
        cperm[s] = cat;
    }
}

// ---------------- tiled fp32 GEMM: C = act(A@B + bias) ----------------
// BM=64, BN=64, BK=16; 256 threads, 4x4 microtile.
template<bool RELU>
__global__ __launch_bounds__(256) void gemm_bias(
    const float* __restrict__ A, const float* __restrict__ B,
    const float* __restrict__ bias, float* __restrict__ Cd,
    int M, int Nn, int K) {
    const int BK = 16;
    __shared__ float As[BK][64 + 4];
    __shared__ float Bs[BK][64];
    int t = threadIdx.x;
    int tx = t & 15, ty = t >> 4;
    int row0 = blockIdx.y * 64, col0 = blockIdx.x * 64;
    float acc[4][4] = {};
    int am = t >> 2, akq = t & 3;   // A tile: row am (0..63), k-quad akq (0..3)
    int br = t >> 4, bc4 = t & 15;  // B tile: k-row br (0..15), col-quad bc4

    for (int kk = 0; kk < K; kk += BK) {
        float4 av = *(const float4*)(A + (size_t)(row0 + am) * K + kk + akq * 4);
        float4 bv = *(const float4*)(B + (size_t)(kk + br) * Nn + col0 + bc4 * 4);
        As[akq * 4 + 0][am] = av.x;
        As[akq * 4 + 1][am] = av.y;
        As[akq * 4 + 2][am] = av.z;
        As[akq * 4 + 3][am] = av.w;
        *(float4*)&Bs[br][bc4 * 4] = bv;
        __syncthreads();
#pragma unroll
        for (int k = 0; k < BK; k++) {
            float ra[4], rb[4];
#pragma unroll
            for (int m = 0; m < 4; m++) ra[m] = As[k][ty * 4 + m];
#pragma unroll
            for (int n2 = 0; n2 < 4; n2++) rb[n2] = Bs[k][tx * 4 + n2];
#pragma unroll
            for (int m = 0; m < 4; m++)
#pragma unroll
                for (int n2 = 0; n2 < 4; n2++) acc[m][n2] += ra[m] * rb[n2];
        }
        __syncthreads();
    }
#pragma unroll
    for (int m = 0; m < 4; m++) {
        int row = row0 + ty * 4 + m;
#pragma unroll
        for (int n2 = 0; n2 < 4; n2++) {
            int col = col0 + tx * 4 + n2;
            float v = acc[m][n2] + bias[col];
            if (RELU) v = fmaxf(v, 0.f);
            Cd[(size_t)row * Nn + col] = v;
        }
    }
}

// ---------------- u[n] = f_x[n] @ w_s[c[n]], grouped by category ----------------
// 8 perm-consecutive samples per block (same category except at boundaries).
__global__ __launch_bounds__(128) void u_kernel(
    const float* __restrict__ fx, const float* __restrict__ wsd,
    const int* __restrict__ perm, const int* __restrict__ cperm,
    float* __restrict__ u) {
    int b = blockIdx.x;
    int e = threadIdx.x;  // 0..127
    __shared__ int spi[8];
    __shared__ int scat[8];
    if (e < 8) {
        spi[e] = perm[b * 8 + e];
        scat[e] = cperm[b * 8 + e];
    }
    __syncthreads();
    __shared__ float sfx[8][Z];
#pragma unroll
    for (int s = 0; s < 8; s++) sfx[s][e] = fx[(size_t)spi[s] * Z + e];
    __syncthreads();
    float acc[8] = {};
    if (scat[0] == scat[7]) {
        const float* W = wsd + (size_t)scat[0] * Z * Z + e;
#pragma unroll 2
        for (int d = 0; d < Z; d++) {
            float wv = W[(size_t)d * Z];
#pragma unroll
            for (int s = 0; s < 8; s++) acc[s] += sfx[s][d] * wv;
        }
    } else {
        for (int s = 0; s < 8; s++) {
            const float* W = wsd + (size_t)scat[s] * Z * Z + e;
            float a = 0.f;
            for (int d = 0; d < Z; d++) a += sfx[s][d] * W[(size_t)d * Z];
            acc[s] = a;
        }
    }
#pragma unroll
    for (int s = 0; s < 8; s++) u[(size_t)spi[s] * Z + e] = acc[s];
}

// ---------------- masked negative term ----------------
// Block = (itile of 32 perm slots) x (j chunk of 512 perm slots).
// For each i, accumulate softplus(u[i] . f_z[j]) over j with same category.
__global__ __launch_bounds__(256) void neg_kernel(
    const float* __restrict__ u, const float* __restrict__ fz,
    const int* __restrict__ perm, const int* __restrict__ cperm,
    const int* __restrict__ offs, float* __restrict__ negsum) {
    const int IT = 32, JT = 32, JC = 512;
    int itile = blockIdx.x, jchunk = blockIdx.y;
    int t = threadIdx.x;

    int cat_lo = cperm[itile * IT];
    int cat_hi = cperm[itile * IT + IT - 1];
    int jlo = max(jchunk * JC, offs[cat_lo]);
    int jhi = min(jchunk * JC + JC, offs[cat_hi + 1]);
    if (jlo >= jhi) return;

    int iloc = t >> 3, lane8 = t & 7;
    int si = itile * IT + iloc;
    int cat_i = cperm[si];
    int pi = perm[si];

    const float4* up = (const float4*)(u + (size_t)pi * Z + lane8 * 16);
    float4 u0 = up[0], u1 = up[1], u2 = up[2], u3 = up[3];

    __shared__ float sfz[JT][Z];
    __shared__ int scat[JT];
    float acc = 0.f;

    for (int j0 = jlo; j0 < jhi; j0 += JT) {
        int nj = min(JT, jhi - j0);
        __syncthreads();
        for (int l = t; l < nj * Z; l += 256) {
            int jl = l >> 7, d = l & 127;
            sfz[jl][d] = fz[(size_t)perm[j0 + jl] * Z + d];
        }
        if (t < nj) scat[t] = cperm[j0 + t];
        __syncthreads();
        for (int jl = 0; jl < nj; jl++) {
            if (scat[jl] != cat_i) continue;
            const float4* fp = (const float4*)&sfz[jl][lane8 * 16];
            float4 f0 = fp[0], f1 = fp[1], f2 = fp[2], f3 = fp[3];
            float dot = u0.x * f0.x + u0.y * f0.y + u0.z * f0.z + u0.w * f0.w
                      + u1.x * f1.x + u1.y * f1.y + u1.z * f1.z + u1.w * f1.w
                      + u2.x * f2.x + u2.y * f2.y + u2.z * f2.z + u2.w * f2.w
                      + u3.x * f3.x + u3.y * f3.y + u3.z * f3.z + u3.w * f3.w;
            dot += __shfl_xor(dot, 1, 8);
            dot += __shfl_xor(dot, 2, 8);
            dot += __shfl_xor(dot, 4, 8);
            acc += softplus_f(dot);
        }
    }
    if (lane8 == 0) atomicAdd(&negsum[pi], acc);
}

// ---------------- final: out = log(T+eps) - log(neg_T+eps) ----------------
__global__ __launch_bounds__(256) void final_kernel(
    const float* __restrict__ u, const float* __restrict__ fz,
    const int* __restrict__ c, const int* __restrict__ cnt,
    const float* __restrict__ negsum, float* __restrict__ out) {
    int gid = blockIdx.x * blockDim.x + threadIdx.x;
    int n = gid >> 6, lane = gid & 63;
    if (n >= N) return;
    float dot = u[(size_t)n * Z + lane] * fz[(size_t)n * Z + lane]
              + u[(size_t)n * Z + 64 + lane] * fz[(size_t)n * Z + 64 + lane];
#pragma unroll
    for (int m = 32; m; m >>= 1) dot += __shfl_xor(dot, m, 64);
    if (lane == 0) {
        float T = softplus_f(dot);
        float nT = negsum[n] / (float)cnt[c[n]];
        out[n] = logf(T + EPS_F) - logf(nT + EPS_F);
    }
}

extern "C" void kernel_launch(void* const* d_in, const int* in_sizes, int n_in,
                              void* d_out, int out_size, void* d_ws, size_t ws_size,
                              hipStream_t stream) {
    const float* x  = (const float*)d_in[0];
    const int*   c  = (const int*)d_in[1];
    const float* z  = (const float*)d_in[2];
    const float* W1 = (const float*)d_in[3];
    const float* b1 = (const float*)d_in[4];
    const float* W2 = (const float*)d_in[5];
    const float* b2 = (const float*)d_in[6];
    const float* Wz = (const float*)d_in[7];
    const float* bz = (const float*)d_in[8];
    const float* w_s = (const float*)d_in[9];
    float* out = (float*)d_out;

    char* p = (char*)d_ws;
    float* H      = (float*)p; p += (size_t)N * HID * 4;
    float* fx     = (float*)p; p += (size_t)N * Z * 4;
    float* fz     = (float*)p; p += (size_t)N * Z * 4;
    float* u      = (float*)p; p += (size_t)N * Z * 4;
    float* negsum = (float*)p; p += (size_t)N * 4;
    int*   perm   = (int*)p;   p += (size_t)N * 4;
    int*   cperm  = (int*)p;   p += (size_t)N * 4;
    int*   cnt    = (int*)p;   p += 256;
    int*   fill   = (int*)p;   p += 256;
    int*   offs   = (int*)p;   p += 256;

    k_init<<<dim3(N / 256), dim3(256), 0, stream>>>(negsum, cnt, fill);

    // f_x = relu(x@W1+b1)@W2+b2 ; f_z = z@Wz+bz
    gemm_bias<true ><<<dim3(HID / 64, N / 64), dim3(256), 0, stream>>>(x, W1, b1, H, N, HID, D_IN);
    gemm_bias<false><<<dim3(Z / 64, N / 64), dim3(256), 0, stream>>>(H, W2, b2, fx, N, Z, HID);
    gemm_bias<false><<<dim3(Z / 64, N / 64), dim3(256), 0, stream>>>(z, Wz, bz, fz, N, Z, Z);

    // category grouping
    k_count<<<dim3(N / 256), dim3(256), 0, stream>>>(c, cnt);
    k_scan<<<dim3(1), dim3(1), 0, stream>>>(cnt, offs);
    k_fill<<<dim3(N / 256), dim3(256), 0, stream>>>(c, fill, offs, perm, cperm);

    // u = f_x @ w_s[c]
    u_kernel<<<dim3(N / 8), dim3(128), 0, stream>>>(fx, w_s, perm, cperm, u);

    // masked softplus-bilinear sums
    neg_kernel<<<dim3(N / 32, N / 512), dim3(256), 0, stream>>>(u, fz, perm, cperm, offs, negsum);

    // final combine
    final_kernel<<<dim3(N * 64 / 256), dim3(256), 0, stream>>>(u, fz, c, cnt, negsum, out);
}

// Round 2
// 238.734 us; speedup vs baseline: 2.7540x; 2.7540x over previous
//
#include <hip/hip_runtime.h>
#include <hip/hip_bf16.h>

#define N 8192
#define D_IN 256
#define HID 512
#define Z 128
#define NCAT 16
#define EPS_F 1e-16f
#define PADMAX 12288   // 16 cats * 768 (mean 512, +11 sigma safety)
#define MAXTILES 192   // PADMAX / 64
#define JT_MAX 12      // 768 / 64

__device__ __forceinline__ float softplus_f(float x) {
    return fmaxf(x, 0.f) + log1pf(expf(-fabsf(x)));
}

// ---------------- init ----------------
__global__ void k_init(float* negsum, int* cnt, int* fill, int* perm_pad) {
    int n = blockIdx.x * blockDim.x + threadIdx.x;
    if (n < N) negsum[n] = 0.f;
    if (n < NCAT) { cnt[n] = 0; fill[n] = 0; }
    if (n < PADMAX) perm_pad[n] = -1;
}

__global__ void k_count(const int* __restrict__ c, int* cnt) {
    int n = blockIdx.x * blockDim.x + threadIdx.x;
    if (n < N) atomicAdd(&cnt[c[n]], 1);
}

__global__ void k_scan(const int* __restrict__ cnt, int* offs, int* offs_pad, int* tile_cat) {
    if (threadIdx.x == 0 && blockIdx.x == 0) {
        int s = 0, sp = 0;
        for (int k = 0; k < NCAT; k++) {
            offs[k] = s; s += cnt[k];
            offs_pad[k] = sp;
            int nt = (cnt[k] + 63) >> 6;
            for (int q = 0; q < nt; q++) tile_cat[(sp >> 6) + q] = k;
            sp += nt << 6;
        }
        offs[NCAT] = s; offs_pad[NCAT] = sp;
        for (int q = sp >> 6; q < MAXTILES; q++) tile_cat[q] = -1;
    }
}

__global__ void k_fill(const int* __restrict__ c, int* fill,
                       const int* __restrict__ offs, const int* __restrict__ offs_pad,
                       int* perm, int* cperm, int* perm_pad) {
    int n = blockIdx.x * blockDim.x + threadIdx.x;
    if (n < N) {
        int cat = c[n];
        int pos = atomicAdd(&fill[cat], 1);
        perm[offs[cat] + pos] = n;
        cperm[offs[cat] + pos] = cat;
        perm_pad[offs_pad[cat] + pos] = n;
    }
}

// ---------------- tiled fp32 GEMM: C = act(A@B + bias) ----------------
template<bool RELU>
__global__ __launch_bounds__(256) void gemm_bias(
    const float* __restrict__ A, const float* __restrict__ B,
    const float* __restrict__ bias, float* __restrict__ Cd,
    int M, int Nn, int K) {
    const int BK = 16;
    __shared__ float As[BK][64 + 4];
    __shared__ float Bs[BK][64];
    int t = threadIdx.x;
    int tx = t & 15, ty = t >> 4;
    int row0 = blockIdx.y * 64, col0 = blockIdx.x * 64;
    float acc[4][4] = {};
    int am = t >> 2, akq = t & 3;
    int br = t >> 4, bc4 = t & 15;

    for (int kk = 0; kk < K; kk += BK) {
        float4 av = *(const float4*)(A + (size_t)(row0 + am) * K + kk + akq * 4);
        float4 bv = *(const float4*)(B + (size_t)(kk + br) * Nn + col0 + bc4 * 4);
        As[akq * 4 + 0][am] = av.x;
        As[akq * 4 + 1][am] = av.y;
        As[akq * 4 + 2][am] = av.z;
        As[akq * 4 + 3][am] = av.w;
        *(float4*)&Bs[br][bc4 * 4] = bv;
        __syncthreads();
#pragma unroll
        for (int k = 0; k < BK; k++) {
            float ra[4], rb[4];
#pragma unroll
            for (int m = 0; m < 4; m++) ra[m] = As[k][ty * 4 + m];
#pragma unroll
            for (int n2 = 0; n2 < 4; n2++) rb[n2] = Bs[k][tx * 4 + n2];
#pragma unroll
            for (int m = 0; m < 4; m++)
#pragma unroll
                for (int n2 = 0; n2 < 4; n2++) acc[m][n2] += ra[m] * rb[n2];
        }
        __syncthreads();
    }
#pragma unroll
    for (int m = 0; m < 4; m++) {
        int row = row0 + ty * 4 + m;
#pragma unroll
        for (int n2 = 0; n2 < 4; n2++) {
            int col = col0 + tx * 4 + n2;
            float v = acc[m][n2] + bias[col];
            if (RELU) v = fmaxf(v, 0.f);
            Cd[(size_t)row * Nn + col] = v;
        }
    }
}

// ---------------- u[n] = f_x[n] @ w_s[c[n]], grouped by category ----------------
__global__ __launch_bounds__(128) void u_kernel(
    const float* __restrict__ fx, const float* __restrict__ wsd,
    const int* __restrict__ perm, const int* __restrict__ cperm,
    float* __restrict__ u) {
    int b = blockIdx.x;
    int e = threadIdx.x;
    __shared__ int spi[8];
    __shared__ int scat[8];
    if (e < 8) {
        spi[e] = perm[b * 8 + e];
        scat[e] = cperm[b * 8 + e];
    }
    __syncthreads();
    __shared__ float sfx[8][Z];
#pragma unroll
    for (int s = 0; s < 8; s++) sfx[s][e] = fx[(size_t)spi[s] * Z + e];
    __syncthreads();
    float acc[8] = {};
    if (scat[0] == scat[7]) {
        const float* W = wsd + (size_t)scat[0] * Z * Z + e;
#pragma unroll 2
        for (int d = 0; d < Z; d++) {
            float wv = W[(size_t)d * Z];
#pragma unroll
            for (int s = 0; s < 8; s++) acc[s] += sfx[s][d] * wv;
        }
    } else {
        for (int s = 0; s < 8; s++) {
            const float* W = wsd + (size_t)scat[s] * Z * Z + e;
            float a = 0.f;
            for (int d = 0; d < Z; d++) a += sfx[s][d] * W[(size_t)d * Z];
            acc[s] = a;
        }
    }
#pragma unroll
    for (int s = 0; s < 8; s++) u[(size_t)spi[s] * Z + e] = acc[s];
}

// ---------------- masked negative term: per-category 64x64 GEMM tiles ----------------
// grid (MAXTILES, JT_MAX); each live block does a single-category 64x64 pair tile,
// K=Z=128 fp32 dot, fused softplus + per-i row sum, one atomic per (i, block).
__global__ __launch_bounds__(256) void neg2_kernel(
    const float* __restrict__ u, const float* __restrict__ fz,
    const int* __restrict__ perm_pad, const int* __restrict__ tile_cat,
    const int* __restrict__ offs_pad, float* __restrict__ negsum) {
    int it = blockIdx.x;
    int cat = tile_cat[it];
    if (cat < 0) return;
    int jbase = offs_pad[cat] + blockIdx.y * 64;
    if (jbase >= offs_pad[cat + 1]) return;
    int ibase = it * 64;

    __shared__ float us[64][132];        // +4 pad: ty-stride reads are 2-way (free)
    __shared__ float fs[64 * 128];       // XOR-swizzled rows: byte ^= (row&7)<<4
    __shared__ int ip[64], jp[64];

    int t = threadIdx.x;
    if (t < 64) ip[t] = perm_pad[ibase + t];
    else if (t < 128) jp[t - 64] = perm_pad[jbase + (t - 64)];

    char* fsb = (char*)fs;
    int rsub = t >> 5, col4 = t & 31;
#pragma unroll
    for (int r = 0; r < 8; r++) {
        int row = r * 8 + rsub;
        int api = perm_pad[ibase + row];
        float4 av = make_float4(0.f, 0.f, 0.f, 0.f);
        if (api >= 0) av = *(const float4*)(u + (size_t)api * Z + col4 * 4);
        *(float4*)&us[row][col4 * 4] = av;
        int bpi = perm_pad[jbase + row];
        float4 bv = make_float4(0.f, 0.f, 0.f, 0.f);
        if (bpi >= 0) bv = *(const float4*)(fz + (size_t)bpi * Z + col4 * 4);
        int byte = (row * 512 + col4 * 16) ^ ((row & 7) << 4);
        *(float4*)(fsb + byte) = bv;
    }
    __syncthreads();

    int tx = t & 15, ty = t >> 4;
    float acc[4][4] = {};
    const float* ur[4];
    int fb[4], fxo[4];
#pragma unroll
    for (int m = 0; m < 4; m++) ur[m] = &us[ty * 4 + m][0];
#pragma unroll
    for (int n2 = 0; n2 < 4; n2++) {
        int row = tx * 4 + n2;
        fb[n2] = row * 512;
        fxo[n2] = (row & 7) << 4;
    }

#pragma unroll 2
    for (int kk = 0; kk < 32; kk++) {
        float4 uf[4], ff[4];
#pragma unroll
        for (int m = 0; m < 4; m++) uf[m] = *(const float4*)(ur[m] + kk * 4);
#pragma unroll
        for (int n2 = 0; n2 < 4; n2++)
            ff[n2] = *(const float4*)(fsb + fb[n2] + ((kk * 16) ^ fxo[n2]));
#pragma unroll
        for (int m = 0; m < 4; m++)
#pragma unroll
            for (int n2 = 0; n2 < 4; n2++)
                acc[m][n2] += uf[m].x * ff[n2].x + uf[m].y * ff[n2].y
                            + uf[m].z * ff[n2].z + uf[m].w * ff[n2].w;
    }

    // epilogue: softplus once per valid pair, per-i partial sums
    float s[4] = {};
#pragma unroll
    for (int m = 0; m < 4; m++)
#pragma unroll
        for (int n2 = 0; n2 < 4; n2++) {
            float sp = softplus_f(acc[m][n2]);
            s[m] += (jp[tx * 4 + n2] >= 0) ? sp : 0.f;
        }
#pragma unroll
    for (int m = 0; m < 4; m++) {
#pragma unroll
        for (int off = 8; off; off >>= 1) s[m] += __shfl_xor(s[m], off, 16);
    }
    if (tx == 0) {
#pragma unroll
        for (int m = 0; m < 4; m++) {
            int pi = ip[ty * 4 + m];
            if (pi >= 0) atomicAdd(&negsum[pi], s[m]);
        }
    }
}

// ---------------- final: out = log(T+eps) - log(neg_T+eps) ----------------
__global__ __launch_bounds__(256) void final_kernel(
    const float* __restrict__ u, const float* __restrict__ fz,
    const int* __restrict__ c, const int* __restrict__ cnt,
    const float* __restrict__ negsum, float* __restrict__ out) {
    int gid = blockIdx.x * blockDim.x + threadIdx.x;
    int n = gid >> 6, lane = gid & 63;
    if (n >= N) return;
    float dot = u[(size_t)n * Z + lane] * fz[(size_t)n * Z + lane]
              + u[(size_t)n * Z + 64 + lane] * fz[(size_t)n * Z + 64 + lane];
#pragma unroll
    for (int m = 32; m; m >>= 1) dot += __shfl_xor(dot, m, 64);
    if (lane == 0) {
        float T = softplus_f(dot);
        float nT = negsum[n] / (float)cnt[c[n]];
        out[n] = logf(T + EPS_F) - logf(nT + EPS_F);
    }
}

extern "C" void kernel_launch(void* const* d_in, const int* in_sizes, int n_in,
                              void* d_out, int out_size, void* d_ws, size_t ws_size,
                              hipStream_t stream) {
    const float* x  = (const float*)d_in[0];
    const int*   c  = (const int*)d_in[1];
    const float* z  = (const float*)d_in[2];
    const float* W1 = (const float*)d_in[3];
    const float* b1 = (const float*)d_in[4];
    const float* W2 = (const float*)d_in[5];
    const float* b2 = (const float*)d_in[6];
    const float* Wz = (const float*)d_in[7];
    const float* bz = (const float*)d_in[8];
    const float* w_s = (const float*)d_in[9];
    float* out = (float*)d_out;

    char* p = (char*)d_ws;
    float* H        = (float*)p; p += (size_t)N * HID * 4;
    float* fx       = (float*)p; p += (size_t)N * Z * 4;
    float* fz       = (float*)p; p += (size_t)N * Z * 4;
    float* u        = (float*)p; p += (size_t)N * Z * 4;
    float* negsum   = (float*)p; p += (size_t)N * 4;
    int*   perm     = (int*)p;   p += (size_t)N * 4;
    int*   cperm    = (int*)p;   p += (size_t)N * 4;
    int*   perm_pad = (int*)p;   p += (size_t)PADMAX * 4;
    int*   cnt      = (int*)p;   p += 256;
    int*   fill     = (int*)p;   p += 256;
    int*   offs     = (int*)p;   p += 256;
    int*   offs_pad = (int*)p;   p += 256;
    int*   tile_cat = (int*)p;   p += MAXTILES * 4;

    k_init<<<dim3(PADMAX / 256), dim3(256), 0, stream>>>(negsum, cnt, fill, perm_pad);

    // f_x = relu(x@W1+b1)@W2+b2 ; f_z = z@Wz+bz
    gemm_bias<true ><<<dim3(HID / 64, N / 64), dim3(256), 0, stream>>>(x, W1, b1, H, N, HID, D_IN);
    gemm_bias<false><<<dim3(Z / 64, N / 64), dim3(256), 0, stream>>>(H, W2, b2, fx, N, Z, HID);
    gemm_bias<false><<<dim3(Z / 64, N / 64), dim3(256), 0, stream>>>(z, Wz, bz, fz, N, Z, Z);

    // category grouping (padded to 64-multiples per category)
    k_count<<<dim3(N / 256), dim3(256), 0, stream>>>(c, cnt);
    k_scan<<<dim3(1), dim3(1), 0, stream>>>(cnt, offs, offs_pad, tile_cat);
    k_fill<<<dim3(N / 256), dim3(256), 0, stream>>>(c, fill, offs, offs_pad, perm, cperm, perm_pad);

    // u = f_x @ w_s[c]
    u_kernel<<<dim3(N / 8), dim3(128), 0, stream>>>(fx, w_s, perm, cperm, u);

    // masked softplus-bilinear sums: per-category tiled GEMM
    neg2_kernel<<<dim3(MAXTILES, JT_MAX), dim3(256), 0, stream>>>(u, fz, perm_pad, tile_cat, offs_pad, negsum);

    // final combine
    final_kernel<<<dim3(N * 64 / 256), dim3(256), 0, stream>>>(u, fz, c, cnt, negsum, out);
}

// Round 3
// 131.946 us; speedup vs baseline: 4.9829x; 1.8093x over previous
//
#include <hip/hip_runtime.h>
#include <hip/hip_bf16.h>

#define N 8192
#define D_IN 256
#define HID 512
#define Z 128
#define NCAT 16
#define EPS_F 1e-16f
#define PADMAX 12288   // 16 cats * 768 (mean 512, +11 sigma safety)
#define MAXTILES 192   // PADMAX / 64
#define JT_MAX 12      // 768 / 64

typedef short bf16x8 __attribute__((ext_vector_type(8)));
typedef float f32x4 __attribute__((ext_vector_type(4)));

__device__ __forceinline__ unsigned short f2bf(float f) {
    unsigned u = __float_as_uint(f);
    unsigned r = u + 0x7FFFu + ((u >> 16) & 1u);
    return (unsigned short)(r >> 16);
}
__device__ __forceinline__ float bf2f(unsigned short s) {
    return __uint_as_float(((unsigned)s) << 16);
}
__device__ __forceinline__ unsigned pack2(float a, float b) {
    return (unsigned)f2bf(a) | ((unsigned)f2bf(b) << 16);
}
__device__ __forceinline__ float softplus_f(float x) {
    return fmaxf(x, 0.f) + log1pf(expf(-fabsf(x)));
}

// ---------------- init / grouping ----------------
__global__ void k_init(float* negsum, int* cnt, int* fill, int* perm_pad) {
    int n = blockIdx.x * blockDim.x + threadIdx.x;
    if (n < N) negsum[n] = 0.f;
    if (n < NCAT) { cnt[n] = 0; fill[n] = 0; }
    if (n < PADMAX) perm_pad[n] = -1;
}

__global__ void k_count(const int* __restrict__ c, int* cnt) {
    int n = blockIdx.x * blockDim.x + threadIdx.x;
    if (n < N) atomicAdd(&cnt[c[n]], 1);
}

__global__ void k_scan(const int* __restrict__ cnt, int* offs_pad, int* tile_cat) {
    if (threadIdx.x == 0 && blockIdx.x == 0) {
        int sp = 0;
        for (int k = 0; k < NCAT; k++) {
            offs_pad[k] = sp;
            int nt = (cnt[k] + 63) >> 6;
            for (int q = 0; q < nt; q++) tile_cat[(sp >> 6) + q] = k;
            sp += nt << 6;
        }
        offs_pad[NCAT] = sp;
        for (int q = sp >> 6; q < MAXTILES; q++) tile_cat[q] = -1;
    }
}

__global__ void k_fill(const int* __restrict__ c, int* fill,
                       const int* __restrict__ offs_pad, int* perm_pad) {
    int n = blockIdx.x * blockDim.x + threadIdx.x;
    if (n < N) {
        int cat = c[n];
        int pos = atomicAdd(&fill[cat], 1);
        perm_pad[offs_pad[cat] + pos] = n;
    }
}

// ---------------- fp32 [R][C] -> bf16 transposed [C][R] ----------------
__global__ __launch_bounds__(256) void k_transpose_bf16(
    const float* __restrict__ in, unsigned short* __restrict__ out, int R, int C) {
    in  += (size_t)blockIdx.z * R * C;
    out += (size_t)blockIdx.z * R * C;
    __shared__ float tile[32][33];
    int tx = threadIdx.x & 31, ty = threadIdx.x >> 5;
    int r0 = blockIdx.y * 32, c0 = blockIdx.x * 32;
#pragma unroll
    for (int q = 0; q < 4; q++)
        tile[ty + 8 * q][tx] = in[(size_t)(r0 + ty + 8 * q) * C + c0 + tx];
    __syncthreads();
#pragma unroll
    for (int q = 0; q < 4; q++)
        out[(size_t)(c0 + ty + 8 * q) * R + r0 + tx] = f2bf(tile[tx][ty + 8 * q]);
}

// ---------------- MFMA GEMM: Cb = act(A @ Bt^T + bias), bf16 out ----------------
// A: [M][K] (fp32 or bf16), Bt: [Nn][K] bf16 (pre-transposed B). BM=BN=64, BK=64.
// 256 threads = 4 waves in 2x2; wave tile 32x32 = 2x2 16x16x32 frags.
template<bool RELU, bool A_F32>
__global__ __launch_bounds__(256) void gemm_mfma(
    const void* __restrict__ Ap, const unsigned short* __restrict__ Bt,
    const float* __restrict__ bias, unsigned short* __restrict__ Cb,
    int M, int Nn, int K) {
    __shared__ char As[64 * 128];
    __shared__ char Bs[64 * 128];
    int t = threadIdx.x;
    int row0 = blockIdx.y * 64, col0 = blockIdx.x * 64;
    int wave = t >> 6, l = t & 63, l15 = l & 15, lg = l >> 4;
    int wm = (wave >> 1) * 32, wn = (wave & 1) * 32;
    f32x4 acc[2][2] = {};

    for (int kk0 = 0; kk0 < K; kk0 += 64) {
#pragma unroll
        for (int q = 0; q < 2; q++) {
            int cid = t + q * 256, row = cid >> 3, ch = cid & 7;
            uint4 w;
            if (A_F32) {
                const float* g = (const float*)Ap + (size_t)(row0 + row) * K + kk0 + ch * 8;
                float4 a0 = *(const float4*)g, a1 = *(const float4*)(g + 4);
                w.x = pack2(a0.x, a0.y); w.y = pack2(a0.z, a0.w);
                w.z = pack2(a1.x, a1.y); w.w = pack2(a1.z, a1.w);
            } else {
                w = *(const uint4*)((const unsigned short*)Ap + (size_t)(row0 + row) * K + kk0 + ch * 8);
            }
            *(uint4*)(As + row * 128 + ((ch ^ (row & 7)) << 4)) = w;
            uint4 wb = *(const uint4*)(Bt + (size_t)(col0 + row) * K + kk0 + ch * 8);
            *(uint4*)(Bs + row * 128 + ((ch ^ (row & 7)) << 4)) = wb;
        }
        __syncthreads();
#pragma unroll
        for (int kk = 0; kk < 2; kk++) {
            int ch = kk * 4 + lg;
            int ra0 = wm + l15, ra1 = ra0 + 16;
            int rb0 = wn + l15, rb1 = rb0 + 16;
            bf16x8 a0 = *(const bf16x8*)(As + ra0 * 128 + ((ch ^ (ra0 & 7)) << 4));
            bf16x8 a1 = *(const bf16x8*)(As + ra1 * 128 + ((ch ^ (ra1 & 7)) << 4));
            bf16x8 b0 = *(const bf16x8*)(Bs + rb0 * 128 + ((ch ^ (rb0 & 7)) << 4));
            bf16x8 b1 = *(const bf16x8*)(Bs + rb1 * 128 + ((ch ^ (rb1 & 7)) << 4));
            acc[0][0] = __builtin_amdgcn_mfma_f32_16x16x32_bf16(a0, b0, acc[0][0], 0, 0, 0);
            acc[0][1] = __builtin_amdgcn_mfma_f32_16x16x32_bf16(a0, b1, acc[0][1], 0, 0, 0);
            acc[1][0] = __builtin_amdgcn_mfma_f32_16x16x32_bf16(a1, b0, acc[1][0], 0, 0, 0);
            acc[1][1] = __builtin_amdgcn_mfma_f32_16x16x32_bf16(a1, b1, acc[1][1], 0, 0, 0);
        }
        __syncthreads();
    }
#pragma unroll
    for (int m = 0; m < 2; m++)
#pragma unroll
        for (int n2 = 0; n2 < 2; n2++)
#pragma unroll
            for (int r = 0; r < 4; r++) {
                int row = row0 + wm + m * 16 + lg * 4 + r;
                int col = col0 + wn + n2 * 16 + l15;
                float v = acc[m][n2][r] + bias[col];
                if (RELU) v = fmaxf(v, 0.f);
                Cb[(size_t)row * Nn + col] = f2bf(v);
            }
}

// ---------------- u tiles: ub[perm rows] = fxb[perm rows] @ wsT[cat]^T ----------------
__global__ __launch_bounds__(256) void u_mfma(
    const unsigned short* __restrict__ fxb, const unsigned short* __restrict__ wsT,
    const int* __restrict__ perm_pad, const int* __restrict__ tile_cat,
    unsigned short* __restrict__ ub) {
    int it = blockIdx.y;
    int cat = tile_cat[it];
    if (cat < 0) return;
    int jn = blockIdx.x;          // which 64-col half of Z=128
    int ibase = it * 64;
    __shared__ char As[64 * 256];
    __shared__ char Bs[64 * 256];
    __shared__ int ip[64];
    int t = threadIdx.x;
    if (t < 64) ip[t] = perm_pad[ibase + t];
    const unsigned short* W = wsT + (size_t)cat * Z * Z + (size_t)jn * 64 * Z;
#pragma unroll
    for (int q = 0; q < 4; q++) {
        int cid = t + q * 256, row = cid >> 4, ch = cid & 15;
        int api = perm_pad[ibase + row];
        uint4 w = make_uint4(0, 0, 0, 0);
        if (api >= 0) w = *(const uint4*)(fxb + (size_t)api * Z + ch * 8);
        *(uint4*)(As + row * 256 + ((ch ^ (row & 7)) << 4)) = w;
        uint4 wb = *(const uint4*)(W + (size_t)row * Z + ch * 8);
        *(uint4*)(Bs + row * 256 + ((ch ^ (row & 7)) << 4)) = wb;
    }
    __syncthreads();
    int wave = t >> 6, l = t & 63, l15 = l & 15, lg = l >> 4;
    int wm = (wave >> 1) * 32, wn = (wave & 1) * 32;
    f32x4 acc[2][2] = {};
#pragma unroll
    for (int kk = 0; kk < 4; kk++) {
        int ch = kk * 4 + lg;
        int ra0 = wm + l15, ra1 = ra0 + 16;
        int rb0 = wn + l15, rb1 = rb0 + 16;
        bf16x8 a0 = *(const bf16x8*)(As + ra0 * 256 + ((ch ^ (ra0 & 7)) << 4));
        bf16x8 a1 = *(const bf16x8*)(As + ra1 * 256 + ((ch ^ (ra1 & 7)) << 4));
        bf16x8 b0 = *(const bf16x8*)(Bs + rb0 * 256 + ((ch ^ (rb0 & 7)) << 4));
        bf16x8 b1 = *(const bf16x8*)(Bs + rb1 * 256 + ((ch ^ (rb1 & 7)) << 4));
        acc[0][0] = __builtin_amdgcn_mfma_f32_16x16x32_bf16(a0, b0, acc[0][0], 0, 0, 0);
        acc[0][1] = __builtin_amdgcn_mfma_f32_16x16x32_bf16(a0, b1, acc[0][1], 0, 0, 0);
        acc[1][0] = __builtin_amdgcn_mfma_f32_16x16x32_bf16(a1, b0, acc[1][0], 0, 0, 0);
        acc[1][1] = __builtin_amdgcn_mfma_f32_16x16x32_bf16(a1, b1, acc[1][1], 0, 0, 0);
    }
#pragma unroll
    for (int m = 0; m < 2; m++)
#pragma unroll
        for (int n2 = 0; n2 < 2; n2++)
#pragma unroll
            for (int r = 0; r < 4; r++) {
                int pi = ip[wm + m * 16 + lg * 4 + r];
                if (pi >= 0)
                    ub[(size_t)pi * Z + jn * 64 + wn + n2 * 16 + l15] = f2bf(acc[m][n2][r]);
            }
}

// ---------------- masked negative term: per-category 64x64 MFMA tiles ----------------
__global__ __launch_bounds__(256) void neg_mfma(
    const unsigned short* __restrict__ ub, const unsigned short* __restrict__ fzb,
    const int* __restrict__ perm_pad, const int* __restrict__ tile_cat,
    const int* __restrict__ offs_pad, float* __restrict__ negsum) {
    int it = blockIdx.y;
    int cat = tile_cat[it];
    if (cat < 0) return;
    int jbase = offs_pad[cat] + blockIdx.x * 64;
    if (jbase >= offs_pad[cat + 1]) return;
    int ibase = it * 64;
    __shared__ char As[64 * 256];
    __shared__ char Bs[64 * 256];
    __shared__ int ip[64], jp[64];
    int t = threadIdx.x;
    if (t < 64) ip[t] = perm_pad[ibase + t];
    else if (t < 128) jp[t - 64] = perm_pad[jbase + t - 64];
#pragma unroll
    for (int q = 0; q < 4; q++) {
        int cid = t + q * 256, row = cid >> 4, ch = cid & 15;
        int api = perm_pad[ibase + row];
        uint4 w = make_uint4(0, 0, 0, 0);
        if (api >= 0) w = *(const uint4*)(ub + (size_t)api * Z + ch * 8);
        *(uint4*)(As + row * 256 + ((ch ^ (row & 7)) << 4)) = w;
        int bpi = perm_pad[jbase + row];
        uint4 wb = make_uint4(0, 0, 0, 0);
        if (bpi >= 0) wb = *(const uint4*)(fzb + (size_t)bpi * Z + ch * 8);
        *(uint4*)(Bs + row * 256 + ((ch ^ (row & 7)) << 4)) = wb;
    }
    __syncthreads();
    int wave = t >> 6, l = t & 63, l15 = l & 15, lg = l >> 4;
    int wm = (wave >> 1) * 32, wn = (wave & 1) * 32;
    f32x4 acc[2][2] = {};
#pragma unroll
    for (int kk = 0; kk < 4; kk++) {
        int ch = kk * 4 + lg;
        int ra0 = wm + l15, ra1 = ra0 + 16;
        int rb0 = wn + l15, rb1 = rb0 + 16;
        bf16x8 a0 = *(const bf16x8*)(As + ra0 * 256 + ((ch ^ (ra0 & 7)) << 4));
        bf16x8 a1 = *(const bf16x8*)(As + ra1 * 256 + ((ch ^ (ra1 & 7)) << 4));
        bf16x8 b0 = *(const bf16x8*)(Bs + rb0 * 256 + ((ch ^ (rb0 & 7)) << 4));
        bf16x8 b1 = *(const bf16x8*)(Bs + rb1 * 256 + ((ch ^ (rb1 & 7)) << 4));
        acc[0][0] = __builtin_amdgcn_mfma_f32_16x16x32_bf16(a0, b0, acc[0][0], 0, 0, 0);
        acc[0][1] = __builtin_amdgcn_mfma_f32_16x16x32_bf16(a0, b1, acc[0][1], 0, 0, 0);
        acc[1][0] = __builtin_amdgcn_mfma_f32_16x16x32_bf16(a1, b0, acc[1][0], 0, 0, 0);
        acc[1][1] = __builtin_amdgcn_mfma_f32_16x16x32_bf16(a1, b1, acc[1][1], 0, 0, 0);
    }
    // epilogue: softplus + j-mask + row sums
    float rs[2][4] = {};
#pragma unroll
    for (int m = 0; m < 2; m++)
#pragma unroll
        for (int n2 = 0; n2 < 2; n2++) {
            int col = wn + n2 * 16 + l15;
            bool jv = jp[col] >= 0;
#pragma unroll
            for (int r = 0; r < 4; r++) {
                float sp = softplus_f(acc[m][n2][r]);
                rs[m][r] += jv ? sp : 0.f;
            }
        }
#pragma unroll
    for (int m = 0; m < 2; m++)
#pragma unroll
        for (int r = 0; r < 4; r++) {
            float v = rs[m][r];
            v += __shfl_xor(v, 1, 16);
            v += __shfl_xor(v, 2, 16);
            v += __shfl_xor(v, 4, 16);
            v += __shfl_xor(v, 8, 16);
            rs[m][r] = v;
        }
    if (l15 == 0) {
#pragma unroll
        for (int m = 0; m < 2; m++)
#pragma unroll
            for (int r = 0; r < 4; r++) {
                int pi = ip[wm + m * 16 + lg * 4 + r];
                if (pi >= 0) atomicAdd(&negsum[pi], rs[m][r]);
            }
    }
}

// ---------------- final: out = log(T+eps) - log(neg_T+eps) ----------------
__global__ __launch_bounds__(256) void final_kernel(
    const unsigned short* __restrict__ ub, const unsigned short* __restrict__ fzb,
    const int* __restrict__ c, const int* __restrict__ cnt,
    const float* __restrict__ negsum, float* __restrict__ out) {
    int gid = blockIdx.x * blockDim.x + threadIdx.x;
    int n = gid >> 6, lane = gid & 63;
    if (n >= N) return;
    float dot = bf2f(ub[(size_t)n * Z + lane]) * bf2f(fzb[(size_t)n * Z + lane])
              + bf2f(ub[(size_t)n * Z + 64 + lane]) * bf2f(fzb[(size_t)n * Z + 64 + lane]);
#pragma unroll
    for (int m = 32; m; m >>= 1) dot += __shfl_xor(dot, m, 64);
    if (lane == 0) {
        float T = softplus_f(dot);
        float nT = negsum[n] / (float)cnt[c[n]];
        out[n] = logf(T + EPS_F) - logf(nT + EPS_F);
    }
}

extern "C" void kernel_launch(void* const* d_in, const int* in_sizes, int n_in,
                              void* d_out, int out_size, void* d_ws, size_t ws_size,
                              hipStream_t stream) {
    const float* x  = (const float*)d_in[0];
    const int*   c  = (const int*)d_in[1];
    const float* z  = (const float*)d_in[2];
    const float* W1 = (const float*)d_in[3];
    const float* b1 = (const float*)d_in[4];
    const float* W2 = (const float*)d_in[5];
    const float* b2 = (const float*)d_in[6];
    const float* Wz = (const float*)d_in[7];
    const float* bz = (const float*)d_in[8];
    const float* w_s = (const float*)d_in[9];
    float* out = (float*)d_out;

    char* p = (char*)d_ws;
    unsigned short* H   = (unsigned short*)p; p += (size_t)N * HID * 2;
    unsigned short* fxb = (unsigned short*)p; p += (size_t)N * Z * 2;
    unsigned short* fzb = (unsigned short*)p; p += (size_t)N * Z * 2;
    unsigned short* ub  = (unsigned short*)p; p += (size_t)N * Z * 2;
    unsigned short* W1t = (unsigned short*)p; p += (size_t)D_IN * HID * 2;
    unsigned short* W2t = (unsigned short*)p; p += (size_t)HID * Z * 2;
    unsigned short* Wzt = (unsigned short*)p; p += (size_t)Z * Z * 2;
    unsigned short* wsT = (unsigned short*)p; p += (size_t)NCAT * Z * Z * 2;
    float* negsum   = (float*)p; p += (size_t)N * 4;
    int*   perm_pad = (int*)p;   p += (size_t)PADMAX * 4;
    int*   cnt      = (int*)p;   p += 256;
    int*   fill     = (int*)p;   p += 256;
    int*   offs_pad = (int*)p;   p += 256;
    int*   tile_cat = (int*)p;   p += MAXTILES * 4;

    k_init<<<dim3(PADMAX / 256), dim3(256), 0, stream>>>(negsum, cnt, fill, perm_pad);

    // weight transposes + bf16 conversion
    k_transpose_bf16<<<dim3(HID / 32, D_IN / 32, 1), dim3(256), 0, stream>>>(W1, W1t, D_IN, HID);
    k_transpose_bf16<<<dim3(Z / 32, HID / 32, 1), dim3(256), 0, stream>>>(W2, W2t, HID, Z);
    k_transpose_bf16<<<dim3(Z / 32, Z / 32, 1), dim3(256), 0, stream>>>(Wz, Wzt, Z, Z);
    k_transpose_bf16<<<dim3(Z / 32, Z / 32, NCAT), dim3(256), 0, stream>>>(w_s, wsT, Z, Z);

    // category grouping
    k_count<<<dim3(N / 256), dim3(256), 0, stream>>>(c, cnt);
    k_scan<<<dim3(1), dim3(64), 0, stream>>>(cnt, offs_pad, tile_cat);
    k_fill<<<dim3(N / 256), dim3(256), 0, stream>>>(c, fill, offs_pad, perm_pad);

    // f_x = relu(x@W1+b1)@W2+b2 ; f_z = z@Wz+bz   (bf16 MFMA)
    gemm_mfma<true,  true ><<<dim3(HID / 64, N / 64), dim3(256), 0, stream>>>(x, W1t, b1, H, N, HID, D_IN);
    gemm_mfma<false, false><<<dim3(Z / 64, N / 64), dim3(256), 0, stream>>>(H, W2t, b2, fxb, N, Z, HID);
    gemm_mfma<false, true ><<<dim3(Z / 64, N / 64), dim3(256), 0, stream>>>(z, Wzt, bz, fzb, N, Z, Z);

    // u = f_x @ w_s[c]  (per-category tiles)
    u_mfma<<<dim3(2, MAXTILES), dim3(256), 0, stream>>>(fxb, wsT, perm_pad, tile_cat, ub);

    // masked softplus-bilinear sums
    neg_mfma<<<dim3(JT_MAX, MAXTILES), dim3(256), 0, stream>>>(ub, fzb, perm_pad, tile_cat, offs_pad, negsum);

    // final combine
    final_kernel<<<dim3(N * 64 / 256), dim3(256), 0, stream>>>(ub, fzb, c, cnt, negsum, out);
}

// Round 4
// 74.174 us; speedup vs baseline: 8.8639x; 1.7789x over previous
//
#include <hip/hip_runtime.h>
#include <hip/hip_bf16.h>

#define N 8192
#define D_IN 256
#define HID 512
#define Z 128
#define NCAT 16
#define EPS_F 1e-16f
#define PADMAX 12288   // 16 cats * 768 (mean 512, +11 sigma safety)
#define MAXTILES 192   // PADMAX / 64
#define JT_MAX 12      // 768 / 64

typedef short bf16x8 __attribute__((ext_vector_type(8)));
typedef float f32x4 __attribute__((ext_vector_type(4)));

__device__ __forceinline__ unsigned short f2bf(float f) {
    unsigned u = __float_as_uint(f);
    unsigned r = u + 0x7FFFu + ((u >> 16) & 1u);
    return (unsigned short)(r >> 16);
}
__device__ __forceinline__ float bf2f(unsigned short s) {
    return __uint_as_float(((unsigned)s) << 16);
}
__device__ __forceinline__ unsigned pack2(float a, float b) {
    return (unsigned)f2bf(a) | ((unsigned)f2bf(b) << 16);
}
__device__ __forceinline__ float softplus_f(float x) {
    return fmaxf(x, 0.f) + log1pf(expf(-fabsf(x)));
}

// ---------------- fused setup: count/scan/tile_cat/perm_pad/negsum/cnt ----------------
__global__ __launch_bounds__(1024) void k_setup(
    const int* __restrict__ c, float* __restrict__ negsum, int* __restrict__ perm_pad,
    int* __restrict__ tile_cat, int* __restrict__ offs_pad_g, int* __restrict__ cnt_g) {
    __shared__ int lcnt[16][17];   // wave-replicated counters (16 waves x 16 cats)
    __shared__ int loff[17];
    __shared__ int lfill[16];
    int t = threadIdx.x;
    int wid = t >> 6;
    for (int i = t; i < 16 * 17; i += 1024) ((int*)lcnt)[i] = 0;
    if (t < 16) lfill[t] = 0;
    for (int n = t; n < N; n += 1024) negsum[n] = 0.f;
    for (int i = t; i < PADMAX; i += 1024) perm_pad[i] = -1;
    __syncthreads();
    for (int n = t; n < N; n += 1024) atomicAdd(&lcnt[wid][c[n]], 1);
    __syncthreads();
    if (t < 16) {
        int s = 0;
        for (int w = 0; w < 16; w++) s += lcnt[w][t];
        lcnt[0][t] = s;
        cnt_g[t] = s;
    }
    __syncthreads();
    if (t == 0) {
        int sp = 0;
        for (int k = 0; k < NCAT; k++) {
            loff[k] = sp;
            sp += ((lcnt[0][k] + 63) >> 6) << 6;
        }
        loff[16] = sp;
    }
    __syncthreads();
    if (t < 17) offs_pad_g[t] = loff[t];
    for (int q = t; q < MAXTILES; q += 1024) {
        int cat = -1;
        for (int k = 0; k < NCAT; k++)
            if (q * 64 >= loff[k] && q * 64 < loff[k + 1]) cat = k;
        tile_cat[q] = cat;
    }
    __syncthreads();   // perm_pad -1 init fully visible before fill
    for (int n = t; n < N; n += 1024) {
        int cat = c[n];
        int pos = atomicAdd(&lfill[cat], 1);
        perm_pad[loff[cat] + pos] = n;
    }
}

// ---------------- fused weight transposes: fp32 [R][C] -> bf16 [C][R] ----------------
__global__ __launch_bounds__(256) void k_weights(
    const float* __restrict__ W1, const float* __restrict__ W2,
    const float* __restrict__ Wz, const float* __restrict__ ws,
    unsigned short* __restrict__ W1t, unsigned short* __restrict__ W2t,
    unsigned short* __restrict__ Wzt, unsigned short* __restrict__ wsT) {
    int b = blockIdx.x;
    const float* in; unsigned short* out; int R, C, r0, c0;
    if (b < 128)      { in = W1; out = W1t; R = D_IN; C = HID; c0 = (b & 15) * 32; r0 = (b >> 4) * 32; }
    else if (b < 192) { int q = b - 128; in = W2; out = W2t; R = HID; C = Z; c0 = (q & 3) * 32; r0 = (q >> 2) * 32; }
    else if (b < 208) { int q = b - 192; in = Wz; out = Wzt; R = Z; C = Z; c0 = (q & 3) * 32; r0 = (q >> 2) * 32; }
    else { int q = b - 208; int m = q >> 4; q &= 15;
           in = ws + (size_t)m * Z * Z; out = wsT + (size_t)m * Z * Z;
           R = Z; C = Z; c0 = (q & 3) * 32; r0 = (q >> 2) * 32; }
    __shared__ float tile[32][33];
    int tx = threadIdx.x & 31, ty = threadIdx.x >> 5;
#pragma unroll
    for (int q = 0; q < 4; q++)
        tile[ty + 8 * q][tx] = in[(size_t)(r0 + ty + 8 * q) * C + c0 + tx];
    __syncthreads();
#pragma unroll
    for (int q = 0; q < 4; q++)
        out[(size_t)(c0 + ty + 8 * q) * R + r0 + tx] = f2bf(tile[tx][ty + 8 * q]);
}

// ---------------- MFMA GEMM body: Cb = act(A @ Bt^T + bias), BM=128 BN=64 BK=64 ----------------
// 256 threads = 4 waves (2 row-groups x 2 col-groups); wave tile 64x32 = 4x2 16x16x32 frags.
__device__ __forceinline__ void gemm_body(
    const void* __restrict__ Ap, bool a_f32, const unsigned short* __restrict__ Bt,
    const float* __restrict__ bias, unsigned short* __restrict__ Cb,
    int Nn, int K, bool relu, int row0, int col0, char* As, char* Bs) {
    int t = threadIdx.x;
    int wave = t >> 6, l = t & 63, l15 = l & 15, lg = l >> 4;
    int wm = (wave >> 1) * 64, wn = (wave & 1) * 32;
    f32x4 acc[4][2] = {};

    for (int kk0 = 0; kk0 < K; kk0 += 64) {
#pragma unroll
        for (int q = 0; q < 4; q++) {   // A: 128 rows x 8 chunks
            int cid = t + q * 256, row = cid >> 3, ch = cid & 7;
            uint4 w;
            if (a_f32) {
                const float* g = (const float*)Ap + (size_t)(row0 + row) * K + kk0 + ch * 8;
                float4 a0 = *(const float4*)g, a1 = *(const float4*)(g + 4);
                w.x = pack2(a0.x, a0.y); w.y = pack2(a0.z, a0.w);
                w.z = pack2(a1.x, a1.y); w.w = pack2(a1.z, a1.w);
            } else {
                w = *(const uint4*)((const unsigned short*)Ap + (size_t)(row0 + row) * K + kk0 + ch * 8);
            }
            *(uint4*)(As + row * 128 + ((ch ^ (row & 7)) << 4)) = w;
        }
#pragma unroll
        for (int q = 0; q < 2; q++) {   // B: 64 rows x 8 chunks
            int cid = t + q * 256, row = cid >> 3, ch = cid & 7;
            uint4 wb = *(const uint4*)(Bt + (size_t)(col0 + row) * K + kk0 + ch * 8);
            *(uint4*)(Bs + row * 128 + ((ch ^ (row & 7)) << 4)) = wb;
        }
        __syncthreads();
#pragma unroll
        for (int kk = 0; kk < 2; kk++) {
            int ch = kk * 4 + lg;
            bf16x8 a[4], bq[2];
#pragma unroll
            for (int m = 0; m < 4; m++) {
                int ra = wm + m * 16 + l15;
                a[m] = *(const bf16x8*)(As + ra * 128 + ((ch ^ (ra & 7)) << 4));
            }
#pragma unroll
            for (int n2 = 0; n2 < 2; n2++) {
                int rb = wn + n2 * 16 + l15;
                bq[n2] = *(const bf16x8*)(Bs + rb * 128 + ((ch ^ (rb & 7)) << 4));
            }
#pragma unroll
            for (int m = 0; m < 4; m++)
#pragma unroll
                for (int n2 = 0; n2 < 2; n2++)
                    acc[m][n2] = __builtin_amdgcn_mfma_f32_16x16x32_bf16(a[m], bq[n2], acc[m][n2], 0, 0, 0);
        }
        __syncthreads();
    }
#pragma unroll
    for (int m = 0; m < 4; m++)
#pragma unroll
        for (int n2 = 0; n2 < 2; n2++)
#pragma unroll
            for (int r = 0; r < 4; r++) {
                int row = row0 + wm + m * 16 + lg * 4 + r;
                int col = col0 + wn + n2 * 16 + l15;
                float v = acc[m][n2][r] + bias[col];
                if (relu) v = fmaxf(v, 0.f);
                Cb[(size_t)row * Nn + col] = f2bf(v);
            }
}

__global__ __launch_bounds__(256) void gemm1_k(
    const float* __restrict__ x, const unsigned short* __restrict__ W1t,
    const float* __restrict__ b1, unsigned short* __restrict__ H) {
    __shared__ char As[128 * 128];
    __shared__ char Bs[64 * 128];
    gemm_body(x, true, W1t, b1, H, HID, D_IN, true, blockIdx.y * 128, blockIdx.x * 64, As, Bs);
}

__global__ __launch_bounds__(256) void gemm23_k(
    const unsigned short* __restrict__ H, const unsigned short* __restrict__ W2t,
    const float* __restrict__ b2, unsigned short* __restrict__ fxb,
    const float* __restrict__ z, const unsigned short* __restrict__ Wzt,
    const float* __restrict__ bz, unsigned short* __restrict__ fzb) {
    __shared__ char As[128 * 128];
    __shared__ char Bs[64 * 128];
    if (blockIdx.z == 0)
        gemm_body(H, false, W2t, b2, fxb, Z, HID, false, blockIdx.y * 128, blockIdx.x * 64, As, Bs);
    else
        gemm_body(z, true, Wzt, bz, fzb, Z, Z, false, blockIdx.y * 128, blockIdx.x * 64, As, Bs);
}

// ---------------- u tiles: ub[perm rows] = fxb[perm rows] @ wsT[cat]^T ----------------
__global__ __launch_bounds__(256) void u_mfma(
    const unsigned short* __restrict__ fxb, const unsigned short* __restrict__ wsT,
    const int* __restrict__ perm_pad, const int* __restrict__ tile_cat,
    unsigned short* __restrict__ ub) {
    int it = blockIdx.y;
    int cat = tile_cat[it];
    if (cat < 0) return;
    int jn = blockIdx.x;          // which 64-col half of Z=128
    int ibase = it * 64;
    __shared__ char As[64 * 256];
    __shared__ char Bs[64 * 256];
    __shared__ int ip[64];
    int t = threadIdx.x;
    if (t < 64) ip[t] = perm_pad[ibase + t];
    const unsigned short* W = wsT + (size_t)cat * Z * Z + (size_t)jn * 64 * Z;
#pragma unroll
    for (int q = 0; q < 4; q++) {
        int cid = t + q * 256, row = cid >> 4, ch = cid & 15;
        int api = perm_pad[ibase + row];
        uint4 w = make_uint4(0, 0, 0, 0);
        if (api >= 0) w = *(const uint4*)(fxb + (size_t)api * Z + ch * 8);
        *(uint4*)(As + row * 256 + ((ch ^ (row & 7)) << 4)) = w;
        uint4 wb = *(const uint4*)(W + (size_t)row * Z + ch * 8);
        *(uint4*)(Bs + row * 256 + ((ch ^ (row & 7)) << 4)) = wb;
    }
    __syncthreads();
    int wave = t >> 6, l = t & 63, l15 = l & 15, lg = l >> 4;
    int wm = (wave >> 1) * 32, wn = (wave & 1) * 32;
    f32x4 acc[2][2] = {};
#pragma unroll
    for (int kk = 0; kk < 4; kk++) {
        int ch = kk * 4 + lg;
        int ra0 = wm + l15, ra1 = ra0 + 16;
        int rb0 = wn + l15, rb1 = rb0 + 16;
        bf16x8 a0 = *(const bf16x8*)(As + ra0 * 256 + ((ch ^ (ra0 & 7)) << 4));
        bf16x8 a1 = *(const bf16x8*)(As + ra1 * 256 + ((ch ^ (ra1 & 7)) << 4));
        bf16x8 b0 = *(const bf16x8*)(Bs + rb0 * 256 + ((ch ^ (rb0 & 7)) << 4));
        bf16x8 b1 = *(const bf16x8*)(Bs + rb1 * 256 + ((ch ^ (rb1 & 7)) << 4));
        acc[0][0] = __builtin_amdgcn_mfma_f32_16x16x32_bf16(a0, b0, acc[0][0], 0, 0, 0);
        acc[0][1] = __builtin_amdgcn_mfma_f32_16x16x32_bf16(a0, b1, acc[0][1], 0, 0, 0);
        acc[1][0] = __builtin_amdgcn_mfma_f32_16x16x32_bf16(a1, b0, acc[1][0], 0, 0, 0);
        acc[1][1] = __builtin_amdgcn_mfma_f32_16x16x32_bf16(a1, b1, acc[1][1], 0, 0, 0);
    }
#pragma unroll
    for (int m = 0; m < 2; m++)
#pragma unroll
        for (int n2 = 0; n2 < 2; n2++)
#pragma unroll
            for (int r = 0; r < 4; r++) {
                int pi = ip[wm + m * 16 + lg * 4 + r];
                if (pi >= 0)
                    ub[(size_t)pi * Z + jn * 64 + wn + n2 * 16 + l15] = f2bf(acc[m][n2][r]);
            }
}

// ---------------- masked negative term: per-category 64x64 MFMA tiles ----------------
__global__ __launch_bounds__(256) void neg_mfma(
    const unsigned short* __restrict__ ub, const unsigned short* __restrict__ fzb,
    const int* __restrict__ perm_pad, const int* __restrict__ tile_cat,
    const int* __restrict__ offs_pad, float* __restrict__ negsum) {
    int it = blockIdx.y;
    int cat = tile_cat[it];
    if (cat < 0) return;
    int jbase = offs_pad[cat] + blockIdx.x * 64;
    if (jbase >= offs_pad[cat + 1]) return;
    int ibase = it * 64;
    __shared__ char As[64 * 256];
    __shared__ char Bs[64 * 256];
    __shared__ int ip[64], jp[64];
    int t = threadIdx.x;
    if (t < 64) ip[t] = perm_pad[ibase + t];
    else if (t < 128) jp[t - 64] = perm_pad[jbase + t - 64];
#pragma unroll
    for (int q = 0; q < 4; q++) {
        int cid = t + q * 256, row = cid >> 4, ch = cid & 15;
        int api = perm_pad[ibase + row];
        uint4 w = make_uint4(0, 0, 0, 0);
        if (api >= 0) w = *(const uint4*)(ub + (size_t)api * Z + ch * 8);
        *(uint4*)(As + row * 256 + ((ch ^ (row & 7)) << 4)) = w;
        int bpi = perm_pad[jbase + row];
        uint4 wb = make_uint4(0, 0, 0, 0);
        if (bpi >= 0) wb = *(const uint4*)(fzb + (size_t)bpi * Z + ch * 8);
        *(uint4*)(Bs + row * 256 + ((ch ^ (row & 7)) << 4)) = wb;
    }
    __syncthreads();
    int wave = t >> 6, l = t & 63, l15 = l & 15, lg = l >> 4;
    int wm = (wave >> 1) * 32, wn = (wave & 1) * 32;
    f32x4 acc[2][2] = {};
#pragma unroll
    for (int kk = 0; kk < 4; kk++) {
        int ch = kk * 4 + lg;
        int ra0 = wm + l15, ra1 = ra0 + 16;
        int rb0 = wn + l15, rb1 = rb0 + 16;
        bf16x8 a0 = *(const bf16x8*)(As + ra0 * 256 + ((ch ^ (ra0 & 7)) << 4));
        bf16x8 a1 = *(const bf16x8*)(As + ra1 * 256 + ((ch ^ (ra1 & 7)) << 4));
        bf16x8 b0 = *(const bf16x8*)(Bs + rb0 * 256 + ((ch ^ (rb0 & 7)) << 4));
        bf16x8 b1 = *(const bf16x8*)(Bs + rb1 * 256 + ((ch ^ (rb1 & 7)) << 4));
        acc[0][0] = __builtin_amdgcn_mfma_f32_16x16x32_bf16(a0, b0, acc[0][0], 0, 0, 0);
        acc[0][1] = __builtin_amdgcn_mfma_f32_16x16x32_bf16(a0, b1, acc[0][1], 0, 0, 0);
        acc[1][0] = __builtin_amdgcn_mfma_f32_16x16x32_bf16(a1, b0, acc[1][0], 0, 0, 0);
        acc[1][1] = __builtin_amdgcn_mfma_f32_16x16x32_bf16(a1, b1, acc[1][1], 0, 0, 0);
    }
    float rs[2][4] = {};
#pragma unroll
    for (int m = 0; m < 2; m++)
#pragma unroll
        for (int n2 = 0; n2 < 2; n2++) {
            int col = wn + n2 * 16 + l15;
            bool jv = jp[col] >= 0;
#pragma unroll
            for (int r = 0; r < 4; r++) {
                float sp = softplus_f(acc[m][n2][r]);
                rs[m][r] += jv ? sp : 0.f;
            }
        }
#pragma unroll
    for (int m = 0; m < 2; m++)
#pragma unroll
        for (int r = 0; r < 4; r++) {
            float v = rs[m][r];
            v += __shfl_xor(v, 1, 16);
            v += __shfl_xor(v, 2, 16);
            v += __shfl_xor(v, 4, 16);
            v += __shfl_xor(v, 8, 16);
            rs[m][r] = v;
        }
    if (l15 == 0) {
#pragma unroll
        for (int m = 0; m < 2; m++)
#pragma unroll
            for (int r = 0; r < 4; r++) {
                int pi = ip[wm + m * 16 + lg * 4 + r];
                if (pi >= 0) atomicAdd(&negsum[pi], rs[m][r]);
            }
    }
}

// ---------------- final: out = log(T+eps) - log(neg_T+eps) ----------------
__global__ __launch_bounds__(256) void final_kernel(
    const unsigned short* __restrict__ ub, const unsigned short* __restrict__ fzb,
    const int* __restrict__ c, const int* __restrict__ cnt,
    const float* __restrict__ negsum, float* __restrict__ out) {
    int gid = blockIdx.x * blockDim.x + threadIdx.x;
    int n = gid >> 6, lane = gid & 63;
    if (n >= N) return;
    float dot = bf2f(ub[(size_t)n * Z + lane]) * bf2f(fzb[(size_t)n * Z + lane])
              + bf2f(ub[(size_t)n * Z + 64 + lane]) * bf2f(fzb[(size_t)n * Z + 64 + lane]);
#pragma unroll
    for (int m = 32; m; m >>= 1) dot += __shfl_xor(dot, m, 64);
    if (lane == 0) {
        float T = softplus_f(dot);
        float nT = negsum[n] / (float)cnt[c[n]];
        out[n] = logf(T + EPS_F) - logf(nT + EPS_F);
    }
}

extern "C" void kernel_launch(void* const* d_in, const int* in_sizes, int n_in,
                              void* d_out, int out_size, void* d_ws, size_t ws_size,
                              hipStream_t stream) {
    const float* x  = (const float*)d_in[0];
    const int*   c  = (const int*)d_in[1];
    const float* z  = (const float*)d_in[2];
    const float* W1 = (const float*)d_in[3];
    const float* b1 = (const float*)d_in[4];
    const float* W2 = (const float*)d_in[5];
    const float* b2 = (const float*)d_in[6];
    const float* Wz = (const float*)d_in[7];
    const float* bz = (const float*)d_in[8];
    const float* w_s = (const float*)d_in[9];
    float* out = (float*)d_out;

    char* p = (char*)d_ws;
    unsigned short* H   = (unsigned short*)p; p += (size_t)N * HID * 2;
    unsigned short* fxb = (unsigned short*)p; p += (size_t)N * Z * 2;
    unsigned short* fzb = (unsigned short*)p; p += (size_t)N * Z * 2;
    unsigned short* ub  = (unsigned short*)p; p += (size_t)N * Z * 2;
    unsigned short* W1t = (unsigned short*)p; p += (size_t)D_IN * HID * 2;
    unsigned short* W2t = (unsigned short*)p; p += (size_t)HID * Z * 2;
    unsigned short* Wzt = (unsigned short*)p; p += (size_t)Z * Z * 2;
    unsigned short* wsT = (unsigned short*)p; p += (size_t)NCAT * Z * Z * 2;
    float* negsum   = (float*)p; p += (size_t)N * 4;
    int*   perm_pad = (int*)p;   p += (size_t)PADMAX * 4;
    int*   cnt      = (int*)p;   p += 256;
    int*   offs_pad = (int*)p;   p += 256;
    int*   tile_cat = (int*)p;   p += MAXTILES * 4;

    // fused grouping + init (1 block)
    k_setup<<<dim3(1), dim3(1024), 0, stream>>>(c, negsum, perm_pad, tile_cat, offs_pad, cnt);

    // fused weight transposes
    k_weights<<<dim3(464), dim3(256), 0, stream>>>(W1, W2, Wz, w_s, W1t, W2t, Wzt, wsT);

    // f_x stage 1: H = relu(x@W1+b1)
    gemm1_k<<<dim3(HID / 64, N / 128), dim3(256), 0, stream>>>(x, W1t, b1, H);

    // f_x stage 2 + f_z fused: fx = H@W2+b2 ; fz = z@Wz+bz
    gemm23_k<<<dim3(Z / 64, N / 128, 2), dim3(256), 0, stream>>>(H, W2t, b2, fxb, z, Wzt, bz, fzb);

    // u = f_x @ w_s[c]  (per-category tiles)
    u_mfma<<<dim3(2, MAXTILES), dim3(256), 0, stream>>>(fxb, wsT, perm_pad, tile_cat, ub);

    // masked softplus-bilinear sums
    neg_mfma<<<dim3(JT_MAX, MAXTILES), dim3(256), 0, stream>>>(ub, fzb, perm_pad, tile_cat, offs_pad, negsum);

    // final combine
    final_kernel<<<dim3(N * 64 / 256), dim3(256), 0, stream>>>(ub, fzb, c, cnt, negsum, out);
}